// Round 5
// baseline (65.327 us; speedup 1.0000x reference)
//
#include <hip/hip_runtime.h>
#include <cstddef>

#define NB 8
#define NN 1024
#define NF 32
#define NIDX 4
#define NTILE 16           // 1024/64
#define NPAIR 136          // NTILE*(NTILE+1)/2

// ---- ws layout (float offsets) ----
#define OFF_ROW   0u
#define OFF_COLP  8192u          // [64][8192]
#define OFF_DINV  532480u
#define OFF_S     540672u        // [8192][8]
#define OFF_P     606208u
#define OFF_R     671744u
#define OFF_WP    737280u        // [65536] atomic accumulator for w = M r
#define OFF_WT    802816u        // [65536] wtot = dinv*(p + w)

#if __has_builtin(__builtin_amdgcn_sinf)
#define FSIN(x) __builtin_amdgcn_sinf(x)   // sin(2*pi*x), |x|<0.5 here
#define FCOS(x) __builtin_amdgcn_cosf(x)
#else
#define FSIN(x) __sinf((x) * 6.283185307179586f)
#define FCOS(x) __cosf((x) * 6.283185307179586f)
#endif

// Fused row+col sums of adj (one read) + zero the wpart atomic accumulator.
__global__ __launch_bounds__(512) void k_sums(const float* __restrict__ adj,
                                              float* __restrict__ rowsum,
                                              float* __restrict__ colpart,
                                              float* __restrict__ wpart) {
  int b = blockIdx.x, strip = blockIdx.y;
  int t = threadIdx.x, lane = t & 63, w = t >> 6;
  { int zid = blockIdx.x*64 + blockIdx.y;            // 512 blocks x 128 = 65536
    if (t < 128) wpart[zid*128 + t] = 0.f; }
  float colreg[16];
  #pragma unroll
  for (int i = 0; i < 16; ++i) colreg[i] = 0.f;
  int r0 = strip*16 + w*2;
  #pragma unroll
  for (int rr = 0; rr < 2; ++rr) {
    const float4* row4 = reinterpret_cast<const float4*>(adj + ((size_t)b*NN + r0 + rr)*NN);
    float rs = 0.f;
    #pragma unroll
    for (int cq = 0; cq < 4; ++cq) {
      float4 v = row4[cq*64 + lane];
      colreg[cq*4+0] += v.x; colreg[cq*4+1] += v.y;
      colreg[cq*4+2] += v.z; colreg[cq*4+3] += v.w;
      rs += (v.x + v.y) + (v.z + v.w);
    }
    #pragma unroll
    for (int o = 32; o > 0; o >>= 1) rs += __shfl_xor(rs, o);
    if (lane == 0) rowsum[b*NN + r0 + rr] = rs;
  }
  __shared__ float cacc[8][NN];
  #pragma unroll
  for (int cq = 0; cq < 4; ++cq)
    #pragma unroll
    for (int x = 0; x < 4; ++x) cacc[w][cq*256 + lane*4 + x] = colreg[cq*4+x];
  __syncthreads();
  for (int c = t; c < NN; c += 512) {
    float s = 0.f;
    #pragma unroll
    for (int ww = 0; ww < 8; ++ww) s += cacc[ww][c];
    colpart[(size_t)strip*(NB*NN) + b*NN + c] = s;
  }
}

// dinv + per-node feature contractions: s=(w0+w2).X, p=(w1+2w2).X, r=dinv*(-2w2).X
__global__ __launch_bounds__(256) void k_prep(const float* __restrict__ Xr, const float* __restrict__ Xi,
                       const float* __restrict__ weight,
                       const float* __restrict__ rowsum, const float* __restrict__ colpart,
                       float* __restrict__ dinv,
                       float* __restrict__ svec, float* __restrict__ pvec, float* __restrict__ rvec) {
  __shared__ float wsm[NIDX*3*NF];
  int t = threadIdx.x;
  for (int e = t; e < NIDX*3*NF; e += 256) wsm[e] = weight[e];
  __syncthreads();
  int gid = blockIdx.x*256 + t;
  float cs = 0.f;
  for (int k = 0; k < 64; ++k) cs += colpart[(size_t)k*(NB*NN) + gid];
  float D = 0.5f*(rowsum[gid] + cs);
  float di = (D > 0.f) ? (1.0f / sqrtf(D)) : 0.f;
  dinv[gid] = di;
  const float* xr = Xr + (size_t)gid*NF;
  const float* xi = Xi + (size_t)gid*NF;
  float acc[NIDX][3][2];
  #pragma unroll
  for (int x = 0; x < NIDX; ++x)
    #pragma unroll
    for (int v = 0; v < 3; ++v) { acc[x][v][0] = 0.f; acc[x][v][1] = 0.f; }
  for (int f = 0; f < NF; ++f) {
    float xrf = xr[f], xif = xi[f];
    #pragma unroll
    for (int x = 0; x < NIDX; ++x) {
      float w0 = wsm[x*96 + f], w1 = wsm[x*96 + 32 + f], w2 = wsm[x*96 + 64 + f];
      float av = w0 + w2, bv = w1 + 2.f*w2, cv = -2.f*w2;
      acc[x][0][0] += av*xrf; acc[x][0][1] += av*xif;
      acc[x][1][0] += bv*xrf; acc[x][1][1] += bv*xif;
      acc[x][2][0] += cv*xrf; acc[x][2][1] += cv*xif;
    }
  }
  #pragma unroll
  for (int x = 0; x < NIDX; ++x) {
    size_t o = (size_t)gid*8 + x*2;
    svec[o] = acc[x][0][0];      svec[o+1] = acc[x][0][1];
    pvec[o] = acc[x][1][0];      pvec[o+1] = acc[x][1][1];
    rvec[o] = di*acc[x][2][0];   rvec[o+1] = di*acc[x][2][1];
  }
}

// wtot = dinv*(p + w); out pre-init = svec + bias (pass2 atomics add on top).
__global__ void k_mid(const float* __restrict__ dinv, const float* __restrict__ pvec,
                      const float* __restrict__ wpart, const float* __restrict__ svec,
                      const float* __restrict__ bias, float* __restrict__ wtot,
                      float* __restrict__ out) {
  int o = blockIdx.x*256 + threadIdx.x;   // 65536
  int g = o >> 3, slot = o & 7, x = slot >> 1, p = slot & 1;
  wtot[o] = dinv[g] * (pvec[o] + wpart[o]);
  out[p*32768 + g*4 + x] = svec[o] + (p ? 0.f : bias[x]);
}

// Hermitian tile-pair pass: block = (pair pid -> ti<=tj, batch b).
// i-side: out_i += sm*e^{+i th}*v_j (v has dinv_j folded); j-side (non-diag):
// out_j += sm*e^{-i th}*v_i (v_i wave-uniform -> scalar loads). Final scale 0.5*dinv_row.
// MODE 0: outacc=wpart (w=Mr). MODE 1: outacc=out (+= M wtot, svec/bias pre-added by k_mid).
template<int MODE>
__global__ __launch_bounds__(512, 4) void k_pass(const float* __restrict__ adj,
                                                 const float* __restrict__ dinv,
                                                 const float* __restrict__ vin,
                                                 float* __restrict__ outacc) {
  __shared__ float Tjs[64][65];          // adj[j][i] tile, pad-65 -> 2-way (free)
  __shared__ float redI[8][8*72];
  __shared__ float redJ[8][64*9];
  int b = blockIdx.y;
  int pid = blockIdx.x;
  int ti = 0, rem = pid;
  while (rem >= NTILE - ti) { rem -= NTILE - ti; ++ti; }
  int tj = ti + rem;
  bool diag = (ti == tj);
  int i0 = ti*64, j0 = tj*64;
  int t = threadIdx.x, lane = t & 63, w = t >> 6;
  int wu = __builtin_amdgcn_readfirstlane(w);
  const float QV[NIDX] = {0.5f, 1.f/3.f, 0.25f, 0.2f};

  #pragma unroll
  for (int m = 0; m < 2; ++m) {
    int e4 = t + 512*m;                  // 1024 float4 = 64x64 tile
    int jj = e4 >> 4, i4 = (e4 & 15) << 2;
    float4 vv = *reinterpret_cast<const float4*>(adj + ((size_t)b*NN + j0 + jj)*NN + i0 + i4);
    float* dst = &Tjs[jj][i4];
    dst[0] = vv.x; dst[1] = vv.y; dst[2] = vv.z; dst[3] = vv.w;
  }
  const float4* vb = reinterpret_cast<const float4*>(vin + ((size_t)b*NN + j0 + lane)*8);
  float4 a4 = vb[0], c4 = vb[1];
  float vrj[NIDX] = {a4.x, a4.z, c4.x, c4.z};
  float vij[NIDX] = {a4.y, a4.w, c4.y, c4.w};
  __syncthreads();

  float accr[8][NIDX], acci[8][NIDX];
  #pragma unroll
  for (int s = 0; s < 8; ++s)
    #pragma unroll
    for (int x = 0; x < NIDX; ++x) { accr[s][x] = 0.f; acci[s][x] = 0.f; }
  float jar[NIDX] = {0.f,0.f,0.f,0.f}, jai[NIDX] = {0.f,0.f,0.f,0.f};

  const float* arbase = adj + ((size_t)b*NN + i0 + wu*8)*NN + j0 + lane;
  const float* vibase = vin + ((size_t)b*NN + i0 + wu*8)*8;   // wave-uniform -> s_load
  #pragma unroll
  for (int s = 0; s < 8; ++s) {
    float ar = arbase[(size_t)s*NN];     // a[i][j], coalesced
    float ac = Tjs[lane][wu*8 + s];      // a[j][i]
    float dd = ar - ac, sm = ar + ac;
    float vri[NIDX], vii[NIDX];
    #pragma unroll
    for (int x = 0; x < NIDX; ++x) { vri[x] = vibase[s*8 + x*2]; vii[x] = vibase[s*8 + x*2 + 1]; }
    #pragma unroll
    for (int x = 0; x < NIDX; ++x) {
      float u = QV[x]*dd;                // revolutions, |u| < 0.5
      float sn = FSIN(u), cw = FCOS(u);
      float tr = cw*vrj[x] - sn*vij[x];
      float tii = cw*vij[x] + sn*vrj[x];
      accr[s][x] += sm*tr;
      acci[s][x] += sm*tii;
      if (!diag) {
        float trc = cw*vri[x] + sn*vii[x];
        float tic = cw*vii[x] - sn*vri[x];
        jar[x] += sm*trc;
        jai[x] += sm*tic;
      }
    }
  }

  // i-side: 8x8 in-wave transpose-reduce (verified R4), then atomics.
  bool b1 = (lane & 1), b2 = (lane & 2), b4 = (lane & 4);
  #pragma unroll
  for (int s = 0; s < 8; ++s) {
    float v0 = accr[s][0], v1 = acci[s][0], v2 = accr[s][1], v3 = acci[s][1];
    float v4 = accr[s][2], v5 = acci[s][2], v6 = accr[s][3], v7 = acci[s][3];
    float k0 = b1 ? v1 : v0, s0 = b1 ? v0 : v1;
    float k1 = b1 ? v3 : v2, s1 = b1 ? v2 : v3;
    float k2 = b1 ? v5 : v4, s2 = b1 ? v4 : v5;
    float k3 = b1 ? v7 : v6, s3 = b1 ? v6 : v7;
    v0 = k0 + __shfl_xor(s0, 1);
    v1 = k1 + __shfl_xor(s1, 1);
    v2 = k2 + __shfl_xor(s2, 1);
    v3 = k3 + __shfl_xor(s3, 1);
    k0 = b2 ? v1 : v0; s0 = b2 ? v0 : v1;
    k1 = b2 ? v3 : v2; s1 = b2 ? v2 : v3;
    v0 = k0 + __shfl_xor(s0, 2);
    v1 = k1 + __shfl_xor(s1, 2);
    k0 = b4 ? v1 : v0; s0 = b4 ? v0 : v1;
    v0 = k0 + __shfl_xor(s0, 4);
    redI[w][s*72 + (lane & 7)*9 + (lane >> 3)] = v0;
  }
  if (!diag) {
    #pragma unroll
    for (int x = 0; x < NIDX; ++x) {
      redJ[w][lane*9 + x*2]     = jar[x];
      redJ[w][lane*9 + x*2 + 1] = jai[x];
    }
  }
  __syncthreads();
  {
    int iloc = w*8 + (lane >> 3), slot = lane & 7;
    float sum = 0.f;
    #pragma unroll
    for (int g = 0; g < 8; ++g) sum += redI[w][(lane >> 3)*72 + slot*9 + g];
    int gi = b*NN + i0 + iloc;
    float val = sum * 0.5f * dinv[gi];
    if constexpr (MODE == 0) atomicAdd(&outacc[(size_t)gi*8 + slot], val);
    else                     atomicAdd(&outacc[(slot & 1)*32768 + gi*4 + (slot >> 1)], val);
  }
  if (!diag) {
    int jloc = t >> 3, slot = t & 7;
    float sum = 0.f;
    #pragma unroll
    for (int ww = 0; ww < 8; ++ww) sum += redJ[ww][jloc*9 + slot];
    int gj = b*NN + j0 + jloc;
    float val = sum * 0.5f * dinv[gj];
    if constexpr (MODE == 0) atomicAdd(&outacc[(size_t)gj*8 + slot], val);
    else                     atomicAdd(&outacc[(slot & 1)*32768 + gj*4 + (slot >> 1)], val);
  }
}

extern "C" void kernel_launch(void* const* d_in, const int* in_sizes, int n_in,
                              void* d_out, int out_size, void* d_ws, size_t ws_size,
                              hipStream_t stream) {
  (void)in_sizes; (void)n_in; (void)out_size; (void)ws_size;
  const float* Xr     = (const float*)d_in[0];
  const float* Xi     = (const float*)d_in[1];
  const float* adj    = (const float*)d_in[2];
  const float* weight = (const float*)d_in[3];
  const float* bias   = (const float*)d_in[4];
  float* ws = (float*)d_ws;
  float* rowsum  = ws + OFF_ROW;
  float* colpart = ws + OFF_COLP;
  float* dinv    = ws + OFF_DINV;
  float* svec    = ws + OFF_S;
  float* pvec    = ws + OFF_P;
  float* rvec    = ws + OFF_R;
  float* wpart   = ws + OFF_WP;
  float* wtot    = ws + OFF_WT;
  float* out = (float*)d_out;

  k_sums<<<dim3(NB, 64), 512, 0, stream>>>(adj, rowsum, colpart, wpart);
  k_prep<<<dim3(NB*NN/256), 256, 0, stream>>>(Xr, Xi, weight, rowsum, colpart, dinv, svec, pvec, rvec);
  k_pass<0><<<dim3(NPAIR, NB), 512, 0, stream>>>(adj, dinv, rvec, wpart);
  k_mid<<<dim3(256), 256, 0, stream>>>(dinv, pvec, wpart, svec, bias, wtot, out);
  k_pass<1><<<dim3(NPAIR, NB), 512, 0, stream>>>(adj, dinv, wtot, out);
}